// Round 6
// baseline (489.894 us; speedup 1.0000x reference)
//
#include <hip/hip_runtime.h>

#define QN 512
#define TN 256
#define INFV 1000000000.0f // matches jnp.float32(1e9)

typedef unsigned long long u64;

// per-lane bit of a wave-uniform 64-bit mask (cndmask with SGPR-pair mask)
#if defined(__has_builtin)
#if __has_builtin(__builtin_amdgcn_inverse_ballot_w64)
#define IBAL(m) __builtin_amdgcn_inverse_ballot_w64(m)
#endif
#endif
#ifndef IBAL
#define IBAL(m) ((bool)(((m) >> l) & 1ull))
#endif

// ---------------------------------------------------------------------------
// Cost matrix: C[b][q][t] = |out[b][q].x - tgt[b][t].x| + |out[b][q].y - tgt[b][t].y|
// ---------------------------------------------------------------------------
__global__ __launch_bounds__(256) void cost_kernel(const float2* __restrict__ outputs,
                                                   const float2* __restrict__ targets,
                                                   float* __restrict__ C) {
    const int t = threadIdx.x;
    const int q = blockIdx.x;
    const int b = blockIdx.y;
    float2 o = outputs[b * QN + q];
    float2 g = targets[b * TN + t];
    C[(size_t)(b * QN + q) * TN + t] = fabsf(o.x - g.x) + fabsf(o.y - g.y);
}

__device__ __forceinline__ float readlane_f(float v, int lane) {
    return __builtin_bit_cast(float, __builtin_amdgcn_readlane(__builtin_bit_cast(int, v), lane));
}

template <int CTRL>
__device__ __forceinline__ float dppminf(float x) {
    int o = __builtin_amdgcn_update_dpp(0, __builtin_bit_cast(int, x), CTRL, 0xF, 0xF, true);
    return fminf(x, __builtin_bit_cast(float, o));
}

#define K8(X) X(0) X(1) X(2) X(3) X(4) X(5) X(6) X(7)
#define R4(X) X(0) X(1) X(2) X(3)

// ---------------------------------------------------------------------------
// Jonker-Volgenant Hungarian, one wave per batch, zero LDS, all-register.
// Wave-uniform bookkeeping (used-masks, matched-masks, index select) on the
// SALU; VALU does only the FP work. Bit-exact FP trajectory vs JAX reference.
// ---------------------------------------------------------------------------
__global__ __launch_bounds__(64, 1) void hung_kernel(const float2* __restrict__ outputs,
                                                     const float2* __restrict__ targets,
                                                     float* __restrict__ out_row,
                                                     float* __restrict__ out_col) {
    const int b = blockIdx.x;
    const int l = threadIdx.x;   // lane 0..63

    // row-distributed state: row r = l + 64*s
#define DECLR(s) float tx##s, ty##s, u##s;
    R4(DECLR)
#define LOADR(s) { float2 g = targets[b * TN + l + 64 * s]; tx##s = g.x; ty##s = g.y; u##s = 0.0f; }
    R4(LOADR)

    // column-distributed state: col j = l + 64*k
#define DECLC(k) float ox##k, oy##k, v##k, minv##k, mk##k; int way##k, p##k; const int jc##k = l + 64 * k;
    K8(DECLC)
#define LOADC(k) { float2 o = outputs[b * QN + l + 64 * k]; ox##k = o.x; oy##k = o.y; v##k = 0.0f; \
                   p##k = -1; way##k = QN; }
    K8(LOADC)

    // matched-column bitmasks (wave-uniform SGPRs)
#define DECLM(s) u64 mm##s = 0ull;
    K8(DECLM)

    for (int i = 0; i < TN; ++i) {
#define INITC(k) minv##k = INFV;
        K8(INITC)
        // per-Dijkstra used masks (SGPR)
#define DECLCM(k) u64 cm##k = 0ull;
        K8(DECLCM)
#define DECLRM(s) u64 rm##s = 0ull;
        R4(DECLRM)

        // fetch row i data (readlane + SALU cselect); mark row i used
        const int irs = i >> 6, irl = i & 63;
        float ui0, txv, tyv;
        {
#define RLROW(s) const float ua##s = readlane_f(u##s, irl), ta##s = readlane_f(tx##s, irl), ya##s = readlane_f(ty##s, irl);
            R4(RLROW)
            float q1 = (irs & 1) ? ua1 : ua0, q2 = (irs & 1) ? ua3 : ua2;
            ui0 = (irs & 2) ? q2 : q1;
            float t1 = (irs & 1) ? ta1 : ta0, t2 = (irs & 1) ? ta3 : ta2;
            txv = (irs & 2) ? t2 : t1;
            float y1 = (irs & 1) ? ya1 : ya0, y2 = (irs & 1) ? ya3 : ya2;
            tyv = (irs & 2) ? y2 : y1;
        }
        {
            const u64 rb = 1ull << irl;
#define MRKRI(s) rm##s = (irs == s) ? (rm##s | rb) : rm##s;
            R4(MRKRI)
        }

        int j0s = QN;
        int jfree;
        for (;;) {
            const int j0v = j0s;
            // ---- scan: relax all columns from the current row ----
#define SCAN(k) { const float dxk = ox##k - txv, dyk = oy##k - tyv; \
                  const float cost = __builtin_fabsf(dxk) + __builtin_fabsf(dyk); \
                  const float cur  = (cost - ui0) - v##k; \
                  const u64 bt  = __ballot(cur < minv##k); \
                  const u64 bt2 = bt & ~cm##k; \
                  minv##k = IBAL(bt)     ? cur  : minv##k; \
                  way##k  = IBAL(bt2)    ? j0v  : way##k; \
                  mk##k   = IBAL(cm##k)  ? INFV : minv##k; }
            K8(SCAN)

            // ---- value reduce: exact wave-wide min (delta) ----
            float lmin = fminf(fminf(fminf(mk0, mk1), fminf(mk2, mk3)),
                               fminf(fminf(mk4, mk5), fminf(mk6, mk7)));
            lmin = dppminf<0x121>(lmin);   // row_ror:1
            lmin = dppminf<0x122>(lmin);   // row_ror:2
            lmin = dppminf<0x124>(lmin);   // row_ror:4
            lmin = dppminf<0x128>(lmin);   // row_ror:8
            lmin = dppminf<0x142>(lmin);   // row_bcast:15
            lmin = dppminf<0x143>(lmin);   // row_bcast:31
            const float delta = readlane_f(lmin, 63);

            // ---- index find: smallest j with mk == delta (first-min) ----
#define EBAL(k) const u64 e##k = __ballot(mk##k == delta);
            K8(EBAL)
            u64 esel = e7; int kb = 7;
            esel = e6 ? e6 : esel; kb = e6 ? 6 : kb;
            esel = e5 ? e5 : esel; kb = e5 ? 5 : kb;
            esel = e4 ? e4 : esel; kb = e4 ? 4 : kb;
            esel = e3 ? e3 : esel; kb = e3 ? 3 : kb;
            esel = e2 ? e2 : esel; kb = e2 ? 2 : kb;
            esel = e1 ? e1 : esel; kb = e1 ? 1 : kb;
            esel = e0 ? e0 : esel; kb = e0 ? 0 : kb;
            const int j1s = (kb << 6) | (int)__builtin_ctzll(esel);

            // ---- dual updates (same ops/order as reference, bit-exact) ----
#define UPDU(s) u##s = IBAL(rm##s) ? (u##s + delta) : u##s;
            R4(UPDU)
#define UPDV(k) { v##k = IBAL(cm##k) ? (v##k - delta) : v##k; minv##k = minv##k - delta; }
            K8(UPDV)

            // ---- termination: SALU matched-bit test ----
            const int cslot = j1s >> 6, clane = j1s & 63;
            u64 mmsel = mm0;
            mmsel = (cslot == 1) ? mm1 : mmsel;
            mmsel = (cslot == 2) ? mm2 : mmsel;
            mmsel = (cslot == 3) ? mm3 : mmsel;
            mmsel = (cslot == 4) ? mm4 : mmsel;
            mmsel = (cslot == 5) ? mm5 : mmsel;
            mmsel = (cslot == 6) ? mm6 : mmsel;
            mmsel = (cslot == 7) ? mm7 : mmsel;
            if (((mmsel >> clane) & 1ull) == 0ull) { jfree = j1s; break; }

            // ---- next row i0 = p[j1]: readlane + SALU cselect ----
#define RLP(k) const int ps##k = __builtin_amdgcn_readlane(p##k, clane);
            K8(RLP)
            int i0s = ps0;
            i0s = (cslot == 1) ? ps1 : i0s;
            i0s = (cslot == 2) ? ps2 : i0s;
            i0s = (cslot == 3) ? ps3 : i0s;
            i0s = (cslot == 4) ? ps4 : i0s;
            i0s = (cslot == 5) ? ps5 : i0s;
            i0s = (cslot == 6) ? ps6 : i0s;
            i0s = (cslot == 7) ? ps7 : i0s;

            const int nrs = i0s >> 6, nrl = i0s & 63;
            {
#define RLROW2(s) const float ub##s = readlane_f(u##s, nrl), tb##s = readlane_f(tx##s, nrl), yb##s = readlane_f(ty##s, nrl);
                R4(RLROW2)
                float q1 = (nrs & 1) ? ub1 : ub0, q2 = (nrs & 1) ? ub3 : ub2;
                ui0 = (nrs & 2) ? q2 : q1;
                float t1 = (nrs & 1) ? tb1 : tb0, t2 = (nrs & 1) ? tb3 : tb2;
                txv = (nrs & 2) ? t2 : t1;
                float y1 = (nrs & 1) ? yb1 : yb0, y2 = (nrs & 1) ? yb3 : yb2;
                tyv = (nrs & 2) ? y2 : y1;
            }

            // ---- marks (pure SALU) ----
            {
                const u64 cb = 1ull << clane;
#define MRKC(k) cm##k = (cslot == k) ? (cm##k | cb) : cm##k;
                K8(MRKC)
                const u64 rb2 = 1ull << nrl;
#define MRKR2(s) rm##s = (nrs == s) ? (rm##s | rb2) : rm##s;
                R4(MRKR2)
            }
            j0s = j1s;
        }

        // ---- augment walk: p[jj] = p[way[jj]] along the chain ----
        {
            int jj = jfree;
            for (;;) {
                const int ws = jj >> 6, wl = jj & 63;
#define RLW(k) const int wsv##k = __builtin_amdgcn_readlane(way##k, wl);
                K8(RLW)
                int jn = wsv0;
                jn = (ws == 1) ? wsv1 : jn;
                jn = (ws == 2) ? wsv2 : jn;
                jn = (ws == 3) ? wsv3 : jn;
                jn = (ws == 4) ? wsv4 : jn;
                jn = (ws == 5) ? wsv5 : jn;
                jn = (ws == 6) ? wsv6 : jn;
                jn = (ws == 7) ? wsv7 : jn;
                int pn;
                if (jn == QN) pn = i;
                else {
                    const int qs = jn >> 6, ql = jn & 63;
#define RLP2(k) const int pt##k = __builtin_amdgcn_readlane(p##k, ql);
                    K8(RLP2)
                    pn = pt0;
                    pn = (qs == 1) ? pt1 : pn;
                    pn = (qs == 2) ? pt2 : pn;
                    pn = (qs == 3) ? pt3 : pn;
                    pn = (qs == 4) ? pt4 : pn;
                    pn = (qs == 5) ? pt5 : pn;
                    pn = (qs == 6) ? pt6 : pn;
                    pn = (qs == 7) ? pt7 : pn;
                }
                const u64 wb = 1ull << wl;
#define SETP(k) { const u64 mbit = (ws == k) ? wb : 0ull; p##k = IBAL(mbit) ? pn : p##k; }
                K8(SETP)
                if (jn == QN) break;
                jj = jn;
            }
            const int fs = jfree >> 6;
            const u64 fb = 1ull << (jfree & 63);
#define SETM(s) mm##s = (fs == s) ? (mm##s | fb) : mm##s;
            K8(SETM)
        }
    }

    // ---- emit matched pairs sorted by query index ----
    int rank_base = 0;
#define EMIT(k) { const int pq = p##k; const bool valid = pq >= 0; \
                  u64 m = __ballot(valid); \
                  int below = __popcll(m & ((1ull << l) - 1ull)); \
                  if (valid) { int r = rank_base + below; \
                               out_row[b * TN + r] = (float)jc##k; \
                               out_col[b * TN + r] = (float)pq; } \
                  rank_base += __popcll(m); }
    K8(EMIT)
}

extern "C" void kernel_launch(void* const* d_in, const int* in_sizes, int n_in,
                              void* d_out, int out_size, void* d_ws, size_t ws_size,
                              hipStream_t stream) {
    const float2* outputs = (const float2*)d_in[0];   // [8,512,2] f32
    const float2* targets = (const float2*)d_in[1];   // [8,256,2] f32
    float* out = (float*)d_out;
    float* out_row = out;                 // [8,256] as float
    float* out_col = out + 8 * TN;        // [8,256] as float
    float* C       = out + 2 * 8 * TN;    // [8,512,256] f32

    dim3 gridC(QN, 8);
    cost_kernel<<<gridC, TN, 0, stream>>>(outputs, targets, C);
    hung_kernel<<<8, 64, 0, stream>>>(outputs, targets, out_row, out_col);
}

// Round 7
// 358.810 us; speedup vs baseline: 1.3653x; 1.3653x over previous
//
#include <hip/hip_runtime.h>

#define QN 512
#define TN 256
#define INFV 1000000000.0f // matches jnp.float32(1e9)

typedef unsigned long long u64;

// per-lane bit of a wave-uniform 64-bit mask (cndmask with SGPR-pair mask)
#if defined(__has_builtin)
#if __has_builtin(__builtin_amdgcn_inverse_ballot_w64)
#define IBAL(m) __builtin_amdgcn_inverse_ballot_w64(m)
#endif
#endif
#ifndef IBAL
#define IBAL(m) ((bool)(((m) >> l) & 1ull))
#endif

// ---------------------------------------------------------------------------
// Cost matrix: C[b][q][t] = |out[b][q].x - tgt[b][t].x| + |out[b][q].y - tgt[b][t].y|
// ---------------------------------------------------------------------------
__global__ __launch_bounds__(256) void cost_kernel(const float2* __restrict__ outputs,
                                                   const float2* __restrict__ targets,
                                                   float* __restrict__ C) {
    const int t = threadIdx.x;
    const int q = blockIdx.x;
    const int b = blockIdx.y;
    float2 o = outputs[b * QN + q];
    float2 g = targets[b * TN + t];
    C[(size_t)(b * QN + q) * TN + t] = fabsf(o.x - g.x) + fabsf(o.y - g.y);
}

__device__ __forceinline__ float readlane_f(float v, int lane) {
    return __builtin_bit_cast(float, __builtin_amdgcn_readlane(__builtin_bit_cast(int, v), lane));
}

template <int CTRL>
__device__ __forceinline__ float dppminf(float x) {
    int o = __builtin_amdgcn_update_dpp(0, __builtin_bit_cast(int, x), CTRL, 0xF, 0xF, true);
    return fminf(x, __builtin_bit_cast(float, o));
}

#define K8(X) X(0) X(1) X(2) X(3) X(4) X(5) X(6) X(7)
#define R4(X) X(0) X(1) X(2) X(3)

// ---------------------------------------------------------------------------
// Jonker-Volgenant Hungarian, one wave per batch, zero LDS, all-register.
// Instruction-minimized: minv==INFV marking (no mk/flags), delta-fold into the
// scan compare, value-DPP reduce + ballot index-find, sel-then-readlane
// uniform lookups. Bit-exact FP trajectory vs the JAX reference.
// ---------------------------------------------------------------------------
__global__ __launch_bounds__(64, 1) void hung_kernel(const float2* __restrict__ outputs,
                                                     const float2* __restrict__ targets,
                                                     float* __restrict__ out_row,
                                                     float* __restrict__ out_col) {
    const int b = blockIdx.x;
    const int l = threadIdx.x;   // lane 0..63

    // row-distributed state: row r = l + 64*s
#define DECLR(s) float tx##s, ty##s, u##s, rf##s;
    R4(DECLR)
#define LOADR(s) { float2 g = targets[b * TN + l + 64 * s]; tx##s = g.x; ty##s = g.y; u##s = 0.0f; }
    R4(LOADR)

    // column-distributed state: col j = l + 64*k
#define DECLC(k) float ox##k, oy##k, v##k, minv##k; int way##k, p##k; const int jc##k = l + 64 * k;
    K8(DECLC)
#define LOADC(k) { float2 o = outputs[b * QN + l + 64 * k]; ox##k = o.x; oy##k = o.y; v##k = 0.0f; \
                   p##k = -1; way##k = QN; }
    K8(LOADC)

    // per-Dijkstra used-column masks (wave-uniform SGPRs)
#define DECLCM(k) u64 cm##k;
    K8(DECLCM)

    for (int i = 0; i < TN; ++i) {
#define INITC(k) minv##k = INFV; cm##k = 0ull;
        K8(INITC)
        // row-used flags (float, feed fmaf duals); row i marked
#define INITRF(s) rf##s = (i == jc##s) ? 1.0f : 0.0f;
        R4(INITRF)

        // fetch row i data: select-then-readlane
        const int irs = i >> 6, irl = i & 63;
        float ui0, txv, tyv;
        {
            float a0 = (irs & 1) ? u1 : u0,  a1 = (irs & 1) ? u3 : u2;
            float b0 = (irs & 1) ? tx1 : tx0, b1 = (irs & 1) ? tx3 : tx2;
            float c0 = (irs & 1) ? ty1 : ty0, c1 = (irs & 1) ? ty3 : ty2;
            ui0 = readlane_f((irs & 2) ? a1 : a0, irl);
            txv = readlane_f((irs & 2) ? b1 : b0, irl);
            tyv = readlane_f((irs & 2) ? c1 : c0, irl);
        }

        float dprev = 0.0f;
        int j0s = QN;
        int jfree;
        for (;;) {
            // ---- scan: relax all columns; delta-fold; used gated by SALU mask ----
#define SCAN(k) { const float cost = __builtin_fabsf(ox##k - txv) + __builtin_fabsf(oy##k - tyv); \
                  const float cur  = (cost - ui0) - v##k; \
                  const float tmp  = minv##k - dprev; \
                  const u64 bt2 = __ballot(cur < tmp) & ~cm##k; \
                  minv##k = IBAL(bt2) ? cur : tmp; \
                  way##k  = IBAL(bt2) ? j0s : way##k; }
            K8(SCAN)

            // ---- value reduce: exact wave-wide min == delta ----
            float lmin = fminf(fminf(fminf(minv0, minv1), fminf(minv2, minv3)),
                               fminf(fminf(minv4, minv5), fminf(minv6, minv7)));
            lmin = dppminf<0x121>(lmin);   // row_ror:1
            lmin = dppminf<0x122>(lmin);   // row_ror:2
            lmin = dppminf<0x124>(lmin);   // row_ror:4
            lmin = dppminf<0x128>(lmin);   // row_ror:8
            lmin = dppminf<0x142>(lmin);   // row_bcast:15
            lmin = dppminf<0x143>(lmin);   // row_bcast:31
            const float delta = readlane_f(lmin, 63);

            // ---- index find: smallest j with minv == delta (first-min) ----
#define EBAL(k) const u64 e##k = __ballot(minv##k == delta);
            K8(EBAL)
            u64 esel = e7; int kb = 7;
            esel = e6 ? e6 : esel; kb = e6 ? 6 : kb;
            esel = e5 ? e5 : esel; kb = e5 ? 5 : kb;
            esel = e4 ? e4 : esel; kb = e4 ? 4 : kb;
            esel = e3 ? e3 : esel; kb = e3 ? 3 : kb;
            esel = e2 ? e2 : esel; kb = e2 ? 2 : kb;
            esel = e1 ? e1 : esel; kb = e1 ? 1 : kb;
            esel = e0 ? e0 : esel; kb = e0 ? 0 : kb;
            const int j1s = (kb << 6) | (int)__builtin_ctzll(esel);
            const int cslot = j1s >> 6, clane = j1s & 63;

            // ---- dual updates (bit-exact: fmaf flag / gated sub) ----
#define UPDU(s) u##s = fmaf(rf##s, delta, u##s);
            R4(UPDU)
#define UPDV(k) { const float vm = v##k - delta; v##k = IBAL(cm##k) ? vm : v##k; }
            K8(UPDV)
            dprev = delta;

            // ---- i0 = p[j1] (select-then-readlane); free column -> done ----
            int psel;
            {
                int a0 = (cslot & 1) ? p1 : p0, a1 = (cslot & 1) ? p3 : p2;
                int a2 = (cslot & 1) ? p5 : p4, a3 = (cslot & 1) ? p7 : p6;
                int b0 = (cslot & 2) ? a1 : a0, b1 = (cslot & 2) ? a3 : a2;
                psel = (cslot & 4) ? b1 : b0;
            }
            const int i0s = __builtin_amdgcn_readlane(psel, clane);
            if (i0s < 0) { jfree = j1s; break; }

            // ---- mark column j1: cm bit + minv := INFV (drift-safe) ----
            const u64 cb = 1ull << clane;
#define MRKC(k) { const u64 mb = (cslot == k) ? cb : 0ull; cm##k |= mb; \
                  minv##k = IBAL(mb) ? INFV : minv##k; }
            K8(MRKC)

            // ---- next row data + row mark ----
            const int nrs = i0s >> 6, nrl = i0s & 63;
            {
                float a0 = (nrs & 1) ? u1 : u0,  a1 = (nrs & 1) ? u3 : u2;
                float b0 = (nrs & 1) ? tx1 : tx0, b1 = (nrs & 1) ? tx3 : tx2;
                float c0 = (nrs & 1) ? ty1 : ty0, c1 = (nrs & 1) ? ty3 : ty2;
                ui0 = readlane_f((nrs & 2) ? a1 : a0, nrl);
                txv = readlane_f((nrs & 2) ? b1 : b0, nrl);
                tyv = readlane_f((nrs & 2) ? c1 : c0, nrl);
            }
#define MARKR(s) rf##s = (i0s == jc##s) ? 1.0f : rf##s;
            R4(MARKR)

            j0s = j1s;
        }

        // ---- augment walk: p[jj] = p[way[jj]] along the chain ----
        {
            int jj = jfree;
            for (;;) {
                const int ws = jj >> 6, wl = jj & 63;
                int wsel;
                {
                    int a0 = (ws & 1) ? way1 : way0, a1 = (ws & 1) ? way3 : way2;
                    int a2 = (ws & 1) ? way5 : way4, a3 = (ws & 1) ? way7 : way6;
                    int b0 = (ws & 2) ? a1 : a0, b1 = (ws & 2) ? a3 : a2;
                    wsel = (ws & 4) ? b1 : b0;
                }
                const int jn = __builtin_amdgcn_readlane(wsel, wl);
                int pn;
                if (jn == QN) pn = i;
                else {
                    const int qs = jn >> 6, ql = jn & 63;
                    int qsel;
                    {
                        int a0 = (qs & 1) ? p1 : p0, a1 = (qs & 1) ? p3 : p2;
                        int a2 = (qs & 1) ? p5 : p4, a3 = (qs & 1) ? p7 : p6;
                        int b0 = (qs & 2) ? a1 : a0, b1 = (qs & 2) ? a3 : a2;
                        qsel = (qs & 4) ? b1 : b0;
                    }
                    pn = __builtin_amdgcn_readlane(qsel, ql);
                }
#define SETP(k) p##k = (jj == jc##k) ? pn : p##k;
                K8(SETP)
                if (jn == QN) break;
                jj = jn;
            }
        }
    }

    // ---- emit matched pairs sorted by query index ----
    int rank_base = 0;
#define EMIT(k) { const int pq = p##k; const bool valid = pq >= 0; \
                  u64 m = __ballot(valid); \
                  int below = __popcll(m & ((1ull << l) - 1ull)); \
                  if (valid) { int r = rank_base + below; \
                               out_row[b * TN + r] = (float)jc##k; \
                               out_col[b * TN + r] = (float)pq; } \
                  rank_base += __popcll(m); }
    K8(EMIT)
}

extern "C" void kernel_launch(void* const* d_in, const int* in_sizes, int n_in,
                              void* d_out, int out_size, void* d_ws, size_t ws_size,
                              hipStream_t stream) {
    const float2* outputs = (const float2*)d_in[0];   // [8,512,2] f32
    const float2* targets = (const float2*)d_in[1];   // [8,256,2] f32
    float* out = (float*)d_out;
    float* out_row = out;                 // [8,256] as float
    float* out_col = out + 8 * TN;        // [8,256] as float
    float* C       = out + 2 * 8 * TN;    // [8,512,256] f32

    dim3 gridC(QN, 8);
    cost_kernel<<<gridC, TN, 0, stream>>>(outputs, targets, C);
    hung_kernel<<<8, 64, 0, stream>>>(outputs, targets, out_row, out_col);
}